// Round 4
// baseline (117781.641 us; speedup 1.0000x reference)
//
#include <hip/hip_runtime.h>

typedef _Float16 half8 __attribute__((ext_vector_type(8)));
typedef float f32x4 __attribute__((ext_vector_type(4)));

#define DIM     64
#define KCODES  4096
#define NROWS   65536
#define BM      64                    // rows per block (one wave-row-set)
#define NBLK    (NROWS / BM)          // 1024
#define TPW     64                    // 16-code tiles per wave (4 waves x 64 = 256 tiles)
#define CAP     32
#define MARGIN  1e-4f
#define SIMSCALE (-7.62939453125e-06f) // -2 / (512*512), exact pow2
#define SHIFT   16.0f

// workspace byte offsets
#define WS_OVFC 64
#define WS_OVFR 128
#define WS_EN    262272
#define WS_EN2   278656
#define WS_EMBT  294912
#define WS_FRAG  1343488

__device__ __forceinline__ float4 ldg4(const float* p) {
  return *reinterpret_cast<const float4*>(p);
}

// ---- ||e_k||^2 (numpy pairwise-8 order, bit-validated) + shifted copy ----
__global__ __launch_bounds__(256) void vq_enorm(const float* __restrict__ emb,
                                                float* __restrict__ en,
                                                float* __restrict__ en2) {
  const int k0 = 4 * threadIdx.x + 1024 * blockIdx.x;
  float4 acc[8];
  #pragma unroll
  for (int j = 0; j < 8; ++j) {
    float4 e = ldg4(emb + j * KCODES + k0);
    acc[j].x = __fmul_rn(e.x, e.x); acc[j].y = __fmul_rn(e.y, e.y);
    acc[j].z = __fmul_rn(e.z, e.z); acc[j].w = __fmul_rn(e.w, e.w);
  }
  #pragma unroll
  for (int i = 1; i < 8; ++i) {
    #pragma unroll
    for (int j = 0; j < 8; ++j) {
      float4 e = ldg4(emb + (8 * i + j) * KCODES + k0);
      acc[j].x = __fadd_rn(acc[j].x, __fmul_rn(e.x, e.x));
      acc[j].y = __fadd_rn(acc[j].y, __fmul_rn(e.y, e.y));
      acc[j].z = __fadd_rn(acc[j].z, __fmul_rn(e.z, e.z));
      acc[j].w = __fadd_rn(acc[j].w, __fmul_rn(e.w, e.w));
    }
  }
  float4 s;
  s.x = __fadd_rn(__fadd_rn(__fadd_rn(acc[0].x, acc[1].x), __fadd_rn(acc[2].x, acc[3].x)),
                  __fadd_rn(__fadd_rn(acc[4].x, acc[5].x), __fadd_rn(acc[6].x, acc[7].x)));
  s.y = __fadd_rn(__fadd_rn(__fadd_rn(acc[0].y, acc[1].y), __fadd_rn(acc[2].y, acc[3].y)),
                  __fadd_rn(__fadd_rn(acc[4].y, acc[5].y), __fadd_rn(acc[6].y, acc[7].y)));
  s.z = __fadd_rn(__fadd_rn(__fadd_rn(acc[0].z, acc[1].z), __fadd_rn(acc[2].z, acc[3].z)),
                  __fadd_rn(__fadd_rn(acc[4].z, acc[5].z), __fadd_rn(acc[6].z, acc[7].z)));
  s.w = __fadd_rn(__fadd_rn(__fadd_rn(acc[0].w, acc[1].w), __fadd_rn(acc[2].w, acc[3].w)),
                  __fadd_rn(__fadd_rn(acc[4].w, acc[5].w), __fadd_rn(acc[6].w, acc[7].w)));
  *reinterpret_cast<float4*>(&en[k0]) = s;
  float4 s2;
  s2.x = s.x + SHIFT; s2.y = s.y + SHIFT; s2.z = s.z + SHIFT; s2.w = s.w + SHIFT;
  *reinterpret_cast<float4*>(&en2[k0]) = s2;
}

// ---- prep: embt [4096][64] f32 + B fragment tensor in MFMA-lane order ----
// frag layout: [tile(256)][kf(2)][part(2)][l4*16+l15][8 halves] -> lane-linear 16B
__global__ __launch_bounds__(256) void prep_t(const float* __restrict__ emb,
                                              float* __restrict__ embt,
                                              _Float16* __restrict__ frag) {
  const int c = blockIdx.x * 256 + threadIdx.x;   // code 0..4095
  const int tile = c >> 4, l15 = c & 15;
  #pragma unroll
  for (int kg = 0; kg < 8; ++kg) {                // k-group of 8
    const int kf = kg >> 2, l4 = kg & 3;
    float v[8]; half8 h, l;
    #pragma unroll
    for (int j = 0; j < 8; ++j) v[j] = emb[(size_t)(kg * 8 + j) * KCODES + c];
    #pragma unroll
    for (int j = 0; j < 8; ++j) {
      const float t = v[j] * 512.0f;              // exact pow2 scale
      const _Float16 hh = (_Float16)t;
      const float rr = t - (float)hh;             // exact residual
      h[j] = hh; l[j] = (_Float16)rr;
    }
    float4 o0, o1;
    o0.x = v[0]; o0.y = v[1]; o0.z = v[2]; o0.w = v[3];
    o1.x = v[4]; o1.y = v[5]; o1.z = v[6]; o1.w = v[7];
    *reinterpret_cast<float4*>(&embt[(size_t)c * DIM + kg * 8])     = o0;
    *reinterpret_cast<float4*>(&embt[(size_t)c * DIM + kg * 8 + 4]) = o1;
    const size_t lane16 = (size_t)(l4 * 16 + l15) * 8;
    _Float16* fh = frag + ((size_t)(tile * 2 + kf) * 2 + 0) * 512 + lane16;
    _Float16* fl = frag + ((size_t)(tile * 2 + kf) * 2 + 1) * 512 + lane16;
    *reinterpret_cast<half8*>(fh) = h;
    *reinterpret_cast<half8*>(fl) = l;
  }
}

// ---- scan: barrier-free MFMA candidate search + exact rescore ----
__global__ __launch_bounds__(256, 3) void vq_scan(
    const float* __restrict__ x, const _Float16* __restrict__ frag,
    const float* __restrict__ en2, const float* __restrict__ embt,
    const float* __restrict__ en, float* __restrict__ out,
    double* __restrict__ red, int* __restrict__ ovfc, int* __restrict__ ovfr) {
  __shared__ unsigned s_thr[BM];
  __shared__ int s_cnt[BM];
  __shared__ unsigned short s_list[BM][CAP];
  __shared__ double s_red[2];

  const int tid = threadIdx.x;
  const int lane = tid & 63;
  const int w = tid >> 6;            // wave 0..3
  const int l15 = lane & 15;
  const int l4 = lane >> 4;
  const int rowbase = blockIdx.x * BM;

  if (tid < BM) { s_thr[tid] = 0x7F800000u; s_cnt[tid] = 0; }

  // A fragments: rows rowbase + mt*16 + l15, k = kf*32 + l4*8 + j (x512 h/l split)
  half8 ah[4][2], al[4][2];
  #pragma unroll
  for (int mt = 0; mt < 4; ++mt)
    #pragma unroll
    for (int kf = 0; kf < 2; ++kf) {
      const float* p = x + (size_t)(rowbase + mt * 16 + l15) * DIM + kf * 32 + l4 * 8;
      const float4 v0 = ldg4(p), v1 = ldg4(p + 4);
      const float vv[8] = {v0.x, v0.y, v0.z, v0.w, v1.x, v1.y, v1.z, v1.w};
      #pragma unroll
      for (int j = 0; j < 8; ++j) {
        const float t = vv[j] * 512.0f;
        const _Float16 hh = (_Float16)t;
        const float rr = t - (float)hh;
        ah[mt][kf][j] = hh; al[mt][kf][j] = (_Float16)rr;
      }
    }
  __syncthreads();   // s_thr/s_cnt init visible

  float rm[4][4], thr[4][4];
  #pragma unroll
  for (int mt = 0; mt < 4; ++mt)
    #pragma unroll
    for (int r4 = 0; r4 < 4; ++r4) { rm[mt][r4] = 3.4e38f; thr[mt][r4] = 3.4e38f; }

  const int t0 = w * TPW;
  half8 BA[4], BB[4];
  float eA, eB;

  auto loadT = [&](int t, half8* B, float& env) {
    const char* fb = (const char*)frag + (size_t)t * 4096 + (size_t)lane * 16;
    B[0] = *reinterpret_cast<const half8*>(fb);            // kf0 high
    B[1] = *reinterpret_cast<const half8*>(fb + 1024);     // kf0 low
    B[2] = *reinterpret_cast<const half8*>(fb + 2048);     // kf1 high
    B[3] = *reinterpret_cast<const half8*>(fb + 3072);     // kf1 low
    env = en2[t * 16 + l15];
  };

  auto compute = [&](const half8* B, float env, int t, bool accept) {
    #pragma unroll
    for (int mt = 0; mt < 4; ++mt) {
      f32x4 acc = {0.f, 0.f, 0.f, 0.f};
      acc = __builtin_amdgcn_mfma_f32_16x16x32_f16(ah[mt][0], B[0], acc, 0, 0, 0);
      acc = __builtin_amdgcn_mfma_f32_16x16x32_f16(ah[mt][0], B[1], acc, 0, 0, 0);
      acc = __builtin_amdgcn_mfma_f32_16x16x32_f16(al[mt][0], B[0], acc, 0, 0, 0);
      acc = __builtin_amdgcn_mfma_f32_16x16x32_f16(ah[mt][1], B[2], acc, 0, 0, 0);
      acc = __builtin_amdgcn_mfma_f32_16x16x32_f16(ah[mt][1], B[3], acc, 0, 0, 0);
      acc = __builtin_amdgcn_mfma_f32_16x16x32_f16(al[mt][1], B[2], acc, 0, 0, 0);
      #pragma unroll
      for (int r4 = 0; r4 < 4; ++r4) {
        const float dt = fmaf(acc[r4], SIMSCALE, env);   // = en+16 - 2*sim > 0
        rm[mt][r4] = __builtin_fminf(rm[mt][r4], dt);
        if (accept && dt <= thr[mt][r4]) {
          const int rloc = mt * 16 + l4 * 4 + r4;
          const int ix = atomicAdd(&s_cnt[rloc], 1);
          if (ix < CAP) s_list[rloc][ix] = (unsigned short)(t * 16 + l15);
        }
      }
    }
  };

  auto publish = [&]() {
    #pragma unroll
    for (int mt = 0; mt < 4; ++mt)
      #pragma unroll
      for (int r4 = 0; r4 < 4; ++r4)
        atomicMin(&s_thr[mt * 16 + l4 * 4 + r4], __float_as_uint(rm[mt][r4]));
  };
  auto refreshThr = [&]() {
    #pragma unroll
    for (int mt = 0; mt < 4; ++mt)
      #pragma unroll
      for (int r4 = 0; r4 < 4; ++r4)
        thr[mt][r4] = __uint_as_float(s_thr[mt * 16 + l4 * 4 + r4]) + MARGIN;
  };

  // prepass: 4 tiles min-only, publish, barrier -> seeded thresholds
  #pragma unroll
  for (int t = 0; t < 4; ++t) { loadT(t0 + t, BA, eA); compute(BA, eA, t0 + t, false); }
  publish();
  __syncthreads();
  refreshThr();

  // main scan: reg double-buffered, no barriers
  loadT(t0, BA, eA);
  for (int i = 0; i < TPW; i += 2) {
    loadT(t0 + i + 1, BB, eB);
    compute(BA, eA, t0 + i, true);
    if (i + 2 < TPW) loadT(t0 + i + 2, BA, eA);
    compute(BB, eB, t0 + i + 1, true);
    if (i & 2) { publish(); refreshThr(); }   // every 4 tiles
  }
  __syncthreads();

  // ---- exact rescore (bit-identical round-0 scoring), output, loss ----
  double s1 = 0.0, s2 = 0.0;
  if (tid < BM) {
    const int grow = rowbase + tid;
    const int cnt = s_cnt[tid];
    if (cnt > CAP) {
      const int gi = atomicAdd(ovfc, 1);
      ovfr[gi] = grow;
    } else {
      float f[DIM];
      #pragma unroll
      for (int j = 0; j < 16; ++j) {
        const float4 v = ldg4(x + (size_t)grow * DIM + 4 * j);
        f[4 * j] = v.x; f[4 * j + 1] = v.y; f[4 * j + 2] = v.z; f[4 * j + 3] = v.w;
      }
      float r8[8];
      #pragma unroll
      for (int j = 0; j < 8; ++j) r8[j] = __fmul_rn(f[j], f[j]);
      #pragma unroll
      for (int i = 1; i < 8; ++i)
        #pragma unroll
        for (int j = 0; j < 8; ++j)
          r8[j] = __fadd_rn(r8[j], __fmul_rn(f[8 * i + j], f[8 * i + j]));
      const float fn = __fadd_rn(
          __fadd_rn(__fadd_rn(r8[0], r8[1]), __fadd_rn(r8[2], r8[3])),
          __fadd_rn(__fadd_rn(r8[4], r8[5]), __fadd_rn(r8[6], r8[7])));
      float dbest = 3.4e38f; int kbest = 0x7FFFFFFF;
      for (int i = 0; i < cnt; ++i) {
        const int k = s_list[tid][i];
        const float* ep = embt + (size_t)k * DIM;
        float dot = 0.f;
        #pragma unroll
        for (int j = 0; j < DIM / 4; ++j) {
          const float4 e4 = ldg4(ep + 4 * j);
          dot = fmaf(f[4 * j + 0], e4.x, dot);
          dot = fmaf(f[4 * j + 1], e4.y, dot);
          dot = fmaf(f[4 * j + 2], e4.z, dot);
          dot = fmaf(f[4 * j + 3], e4.w, dot);
        }
        const float d = __fsub_rn(__fadd_rn(fn, en[k]), __fmul_rn(2.0f, dot));
        if (d < dbest || (d == dbest && k < kbest)) { dbest = d; kbest = k; }
      }
      const float* qp = embt + (size_t)kbest * DIM;
      #pragma unroll
      for (int j = 0; j < 16; ++j) {
        const float4 q = ldg4(qp + 4 * j);
        *reinterpret_cast<float4*>(&out[(size_t)grow * DIM + 4 * j]) = q;
        const float d0 = __fsub_rn(q.x, f[4 * j + 0]);
        const float d1 = __fsub_rn(q.y, f[4 * j + 1]);
        const float d2 = __fsub_rn(q.z, f[4 * j + 2]);
        const float d3 = __fsub_rn(q.w, f[4 * j + 3]);
        s1 += ((double)d0 + (double)d1) + ((double)d2 + (double)d3);
        s2 += ((double)d0 * d0 + (double)d1 * d1) + ((double)d2 * d2 + (double)d3 * d3);
      }
    }
    // wave-0 reduction (tid<64 == wave 0)
    #pragma unroll
    for (int off = 32; off > 0; off >>= 1) {
      s1 += __shfl_down(s1, off, 64);
      s2 += __shfl_down(s2, off, 64);
    }
    if (tid == 0) { atomicAdd(&red[0], s1); atomicAdd(&red[1], s2); }
  }
  (void)s_red;
}

// ---- fallback: full exact scan for overflow rows (expected 0) ----
__global__ __launch_bounds__(256) void vq_fallback(
    const float* __restrict__ x, const float* __restrict__ embt,
    const float* __restrict__ en, float* __restrict__ out,
    double* __restrict__ red, const int* __restrict__ ovfc,
    const int* __restrict__ ovfr) {
  const int n = *ovfc;
  const int gw = (blockIdx.x * 256 + threadIdx.x) >> 6;
  const int lane = threadIdx.x & 63;
  const int nw = gridDim.x * 4;
  for (int i = gw; i < n; i += nw) {
    const int row = ovfr[i];
    float f[DIM];
    #pragma unroll
    for (int j = 0; j < 16; ++j) {
      const float4 v = ldg4(x + (size_t)row * DIM + 4 * j);
      f[4 * j] = v.x; f[4 * j + 1] = v.y; f[4 * j + 2] = v.z; f[4 * j + 3] = v.w;
    }
    float r8[8];
    #pragma unroll
    for (int j = 0; j < 8; ++j) r8[j] = __fmul_rn(f[j], f[j]);
    #pragma unroll
    for (int ii = 1; ii < 8; ++ii)
      #pragma unroll
      for (int j = 0; j < 8; ++j)
        r8[j] = __fadd_rn(r8[j], __fmul_rn(f[8 * ii + j], f[8 * ii + j]));
    const float fn = __fadd_rn(
        __fadd_rn(__fadd_rn(r8[0], r8[1]), __fadd_rn(r8[2], r8[3])),
        __fadd_rn(__fadd_rn(r8[4], r8[5]), __fadd_rn(r8[6], r8[7])));
    float dbest = 3.4e38f; int kbest = 0x7FFFFFFF;
    for (int j = 0; j < KCODES / 64; ++j) {
      const int k = j * 64 + lane;
      const float* ep = embt + (size_t)k * DIM;
      float dot = 0.f;
      #pragma unroll
      for (int jj = 0; jj < 16; ++jj) {
        const float4 e4 = ldg4(ep + 4 * jj);
        dot = fmaf(f[4 * jj + 0], e4.x, dot);
        dot = fmaf(f[4 * jj + 1], e4.y, dot);
        dot = fmaf(f[4 * jj + 2], e4.z, dot);
        dot = fmaf(f[4 * jj + 3], e4.w, dot);
      }
      const float d = __fsub_rn(__fadd_rn(fn, en[k]), __fmul_rn(2.0f, dot));
      if (d < dbest) { dbest = d; kbest = k; }
    }
    #pragma unroll
    for (int off = 32; off > 0; off >>= 1) {
      const float d2 = __shfl_xor(dbest, off, 64);
      const int k2 = __shfl_xor(kbest, off, 64);
      if (d2 < dbest || (d2 == dbest && k2 < kbest)) { dbest = d2; kbest = k2; }
    }
    double s1 = 0.0, s2 = 0.0;
    if (lane < 16) {
      const float4 q = ldg4(embt + (size_t)kbest * DIM + lane * 4);
      *reinterpret_cast<float4*>(&out[(size_t)row * DIM + lane * 4]) = q;
      const float d0 = __fsub_rn(q.x, f[lane * 4 + 0]);
      const float d1 = __fsub_rn(q.y, f[lane * 4 + 1]);
      const float d2 = __fsub_rn(q.z, f[lane * 4 + 2]);
      const float d3 = __fsub_rn(q.w, f[lane * 4 + 3]);
      s1 = ((double)d0 + (double)d1) + ((double)d2 + (double)d3);
      s2 = ((double)d0 * d0 + (double)d1 * d1) + ((double)d2 * d2 + (double)d3 * d3);
    }
    #pragma unroll
    for (int off = 32; off > 0; off >>= 1) {
      s1 += __shfl_down(s1, off, 64);
      s2 += __shfl_down(s2, off, 64);
    }
    if (lane == 0) { atomicAdd(&red[0], s1); atomicAdd(&red[1], s2); }
  }
}

__global__ void vq_loss(const double* __restrict__ red, float* __restrict__ out) {
  const double inv = 1.0 / (double)((long long)NROWS * DIM);
  const double m1 = red[0] * inv;
  const double m2 = red[1] * inv;
  out[(long long)NROWS * DIM] = (float)(0.25 * m1 * m1 + m2);
}

extern "C" void kernel_launch(void* const* d_in, const int* in_sizes, int n_in,
                              void* d_out, int out_size, void* d_ws, size_t ws_size,
                              hipStream_t stream) {
  const float* x   = (const float*)d_in[0];
  const float* emb = (const float*)d_in[1];
  float* out = (float*)d_out;
  char* ws = (char*)d_ws;
  double*    red  = (double*)ws;
  int*       ovfc = (int*)(ws + WS_OVFC);
  int*       ovfr = (int*)(ws + WS_OVFR);
  float*     en   = (float*)(ws + WS_EN);
  float*     en2  = (float*)(ws + WS_EN2);
  float*     embt = (float*)(ws + WS_EMBT);
  _Float16*  frag = (_Float16*)(ws + WS_FRAG);
  hipMemsetAsync(d_ws, 0, 128, stream);
  vq_enorm<<<4, 256, 0, stream>>>(emb, en, en2);
  prep_t<<<16, 256, 0, stream>>>(emb, embt, frag);
  vq_scan<<<NBLK, 256, 0, stream>>>(x, frag, en2, embt, en, out, red, ovfc, ovfr);
  vq_fallback<<<16, 256, 0, stream>>>(x, embt, en, out, red, ovfc, ovfr);
  vq_loss<<<1, 1, 0, stream>>>(red, out);
}

// Round 5
// 236.060 us; speedup vs baseline: 498.9482x; 498.9482x over previous
//
#include <hip/hip_runtime.h>

typedef _Float16 half8 __attribute__((ext_vector_type(8)));
typedef float f32x4 __attribute__((ext_vector_type(4)));

#define DIM     64
#define KCODES  4096
#define NROWS   65536
#define BM      64                    // rows per block (one wave-row-set)
#define NBLK    (NROWS / BM)          // 1024
#define TPW     64                    // 16-code tiles per wave (4 waves x 64 = 256 tiles)
#define CAP     32
#define MARGIN  1e-4f
#define SIMSCALE (-7.62939453125e-06f) // -2 / (512*512), exact pow2
#define SHIFT   16.0f

// workspace byte offsets (FIXED round 5: en2 was 128B short -> overlapped embt,
// poisoning dt for codes 4064..4095 and overflowing every row to the fallback)
#define WS_OVFC 64
#define WS_OVFR 128
#define WS_EN    262272   // 4096 f32
#define WS_EN2   278656   // 4096 f32  (ends 295040)
#define WS_EMBT  295040   // 4096*64 f32 = 1048576 B (ends 1343616)
#define WS_FRAG  1343616  // 256 tiles * 4096 B = 1048576 B (ends 2392192)

__device__ __forceinline__ float4 ldg4(const float* p) {
  return *reinterpret_cast<const float4*>(p);
}

// ---- ||e_k||^2 (numpy pairwise-8 order, bit-validated) + shifted copy ----
__global__ __launch_bounds__(256) void vq_enorm(const float* __restrict__ emb,
                                                float* __restrict__ en,
                                                float* __restrict__ en2) {
  const int k0 = 4 * threadIdx.x + 1024 * blockIdx.x;
  float4 acc[8];
  #pragma unroll
  for (int j = 0; j < 8; ++j) {
    float4 e = ldg4(emb + j * KCODES + k0);
    acc[j].x = __fmul_rn(e.x, e.x); acc[j].y = __fmul_rn(e.y, e.y);
    acc[j].z = __fmul_rn(e.z, e.z); acc[j].w = __fmul_rn(e.w, e.w);
  }
  #pragma unroll
  for (int i = 1; i < 8; ++i) {
    #pragma unroll
    for (int j = 0; j < 8; ++j) {
      float4 e = ldg4(emb + (8 * i + j) * KCODES + k0);
      acc[j].x = __fadd_rn(acc[j].x, __fmul_rn(e.x, e.x));
      acc[j].y = __fadd_rn(acc[j].y, __fmul_rn(e.y, e.y));
      acc[j].z = __fadd_rn(acc[j].z, __fmul_rn(e.z, e.z));
      acc[j].w = __fadd_rn(acc[j].w, __fmul_rn(e.w, e.w));
    }
  }
  float4 s;
  s.x = __fadd_rn(__fadd_rn(__fadd_rn(acc[0].x, acc[1].x), __fadd_rn(acc[2].x, acc[3].x)),
                  __fadd_rn(__fadd_rn(acc[4].x, acc[5].x), __fadd_rn(acc[6].x, acc[7].x)));
  s.y = __fadd_rn(__fadd_rn(__fadd_rn(acc[0].y, acc[1].y), __fadd_rn(acc[2].y, acc[3].y)),
                  __fadd_rn(__fadd_rn(acc[4].y, acc[5].y), __fadd_rn(acc[6].y, acc[7].y)));
  s.z = __fadd_rn(__fadd_rn(__fadd_rn(acc[0].z, acc[1].z), __fadd_rn(acc[2].z, acc[3].z)),
                  __fadd_rn(__fadd_rn(acc[4].z, acc[5].z), __fadd_rn(acc[6].z, acc[7].z)));
  s.w = __fadd_rn(__fadd_rn(__fadd_rn(acc[0].w, acc[1].w), __fadd_rn(acc[2].w, acc[3].w)),
                  __fadd_rn(__fadd_rn(acc[4].w, acc[5].w), __fadd_rn(acc[6].w, acc[7].w)));
  *reinterpret_cast<float4*>(&en[k0]) = s;
  float4 s2;
  s2.x = s.x + SHIFT; s2.y = s.y + SHIFT; s2.z = s.z + SHIFT; s2.w = s.w + SHIFT;
  *reinterpret_cast<float4*>(&en2[k0]) = s2;
}

// ---- prep: embt [4096][64] f32 + B fragment tensor in MFMA-lane order ----
// frag layout: [tile(256)][kf(2)][part(2)][l4*16+l15][8 halves] -> lane-linear 16B
__global__ __launch_bounds__(256) void prep_t(const float* __restrict__ emb,
                                              float* __restrict__ embt,
                                              _Float16* __restrict__ frag) {
  const int c = blockIdx.x * 256 + threadIdx.x;   // code 0..4095
  const int tile = c >> 4, l15 = c & 15;
  #pragma unroll
  for (int kg = 0; kg < 8; ++kg) {                // k-group of 8
    const int kf = kg >> 2, l4 = kg & 3;
    float v[8]; half8 h, l;
    #pragma unroll
    for (int j = 0; j < 8; ++j) v[j] = emb[(size_t)(kg * 8 + j) * KCODES + c];
    #pragma unroll
    for (int j = 0; j < 8; ++j) {
      const float t = v[j] * 512.0f;              // exact pow2 scale
      const _Float16 hh = (_Float16)t;
      const float rr = t - (float)hh;             // exact residual
      h[j] = hh; l[j] = (_Float16)rr;
    }
    float4 o0, o1;
    o0.x = v[0]; o0.y = v[1]; o0.z = v[2]; o0.w = v[3];
    o1.x = v[4]; o1.y = v[5]; o1.z = v[6]; o1.w = v[7];
    *reinterpret_cast<float4*>(&embt[(size_t)c * DIM + kg * 8])     = o0;
    *reinterpret_cast<float4*>(&embt[(size_t)c * DIM + kg * 8 + 4]) = o1;
    const size_t lane16 = (size_t)(l4 * 16 + l15) * 8;
    _Float16* fh = frag + ((size_t)(tile * 2 + kf) * 2 + 0) * 512 + lane16;
    _Float16* fl = frag + ((size_t)(tile * 2 + kf) * 2 + 1) * 512 + lane16;
    *reinterpret_cast<half8*>(fh) = h;
    *reinterpret_cast<half8*>(fl) = l;
  }
}

// ---- scan: barrier-free MFMA candidate search + exact rescore ----
__global__ __launch_bounds__(256, 3) void vq_scan(
    const float* __restrict__ x, const _Float16* __restrict__ frag,
    const float* __restrict__ en2, const float* __restrict__ embt,
    const float* __restrict__ en, float* __restrict__ out,
    double* __restrict__ red, int* __restrict__ ovfc, int* __restrict__ ovfr) {
  __shared__ unsigned s_thr[BM];
  __shared__ int s_cnt[BM];
  __shared__ unsigned short s_list[BM][CAP];

  const int tid = threadIdx.x;
  const int lane = tid & 63;
  const int w = tid >> 6;            // wave 0..3
  const int l15 = lane & 15;
  const int l4 = lane >> 4;
  const int rowbase = blockIdx.x * BM;

  if (tid < BM) { s_thr[tid] = 0x7F800000u; s_cnt[tid] = 0; }

  // A fragments: rows rowbase + mt*16 + l15, k = kf*32 + l4*8 + j (x512 h/l split)
  half8 ah[4][2], al[4][2];
  #pragma unroll
  for (int mt = 0; mt < 4; ++mt)
    #pragma unroll
    for (int kf = 0; kf < 2; ++kf) {
      const float* p = x + (size_t)(rowbase + mt * 16 + l15) * DIM + kf * 32 + l4 * 8;
      const float4 v0 = ldg4(p), v1 = ldg4(p + 4);
      const float vv[8] = {v0.x, v0.y, v0.z, v0.w, v1.x, v1.y, v1.z, v1.w};
      #pragma unroll
      for (int j = 0; j < 8; ++j) {
        const float t = vv[j] * 512.0f;
        const _Float16 hh = (_Float16)t;
        const float rr = t - (float)hh;
        ah[mt][kf][j] = hh; al[mt][kf][j] = (_Float16)rr;
      }
    }
  __syncthreads();   // s_thr/s_cnt init visible

  float rm[4][4], thr[4][4];
  #pragma unroll
  for (int mt = 0; mt < 4; ++mt)
    #pragma unroll
    for (int r4 = 0; r4 < 4; ++r4) { rm[mt][r4] = 3.4e38f; thr[mt][r4] = 3.4e38f; }

  const int t0 = w * TPW;
  half8 BA[4], BB[4];
  float eA, eB;

  auto loadT = [&](int t, half8* B, float& env) {
    const char* fb = (const char*)frag + (size_t)t * 4096 + (size_t)lane * 16;
    B[0] = *reinterpret_cast<const half8*>(fb);            // kf0 high
    B[1] = *reinterpret_cast<const half8*>(fb + 1024);     // kf0 low
    B[2] = *reinterpret_cast<const half8*>(fb + 2048);     // kf1 high
    B[3] = *reinterpret_cast<const half8*>(fb + 3072);     // kf1 low
    env = en2[t * 16 + l15];
  };

  auto compute = [&](const half8* B, float env, int t, bool accept) {
    #pragma unroll
    for (int mt = 0; mt < 4; ++mt) {
      f32x4 acc = {0.f, 0.f, 0.f, 0.f};
      acc = __builtin_amdgcn_mfma_f32_16x16x32_f16(ah[mt][0], B[0], acc, 0, 0, 0);
      acc = __builtin_amdgcn_mfma_f32_16x16x32_f16(ah[mt][0], B[1], acc, 0, 0, 0);
      acc = __builtin_amdgcn_mfma_f32_16x16x32_f16(al[mt][0], B[0], acc, 0, 0, 0);
      acc = __builtin_amdgcn_mfma_f32_16x16x32_f16(ah[mt][1], B[2], acc, 0, 0, 0);
      acc = __builtin_amdgcn_mfma_f32_16x16x32_f16(ah[mt][1], B[3], acc, 0, 0, 0);
      acc = __builtin_amdgcn_mfma_f32_16x16x32_f16(al[mt][1], B[2], acc, 0, 0, 0);
      #pragma unroll
      for (int r4 = 0; r4 < 4; ++r4) {
        const float dt = fmaf(acc[r4], SIMSCALE, env);   // = en+16 - 2*sim > 0
        rm[mt][r4] = __builtin_fminf(rm[mt][r4], dt);
        if (accept && dt <= thr[mt][r4]) {
          const int rloc = mt * 16 + l4 * 4 + r4;
          const int ix = atomicAdd(&s_cnt[rloc], 1);
          if (ix < CAP) s_list[rloc][ix] = (unsigned short)(t * 16 + l15);
        }
      }
    }
  };

  auto publish = [&]() {
    #pragma unroll
    for (int mt = 0; mt < 4; ++mt)
      #pragma unroll
      for (int r4 = 0; r4 < 4; ++r4)
        atomicMin(&s_thr[mt * 16 + l4 * 4 + r4], __float_as_uint(rm[mt][r4]));
  };
  auto refreshThr = [&]() {
    #pragma unroll
    for (int mt = 0; mt < 4; ++mt)
      #pragma unroll
      for (int r4 = 0; r4 < 4; ++r4)
        thr[mt][r4] = __uint_as_float(s_thr[mt * 16 + l4 * 4 + r4]) + MARGIN;
  };

  // prepass: 4 tiles min-only, publish, barrier -> seeded thresholds
  #pragma unroll
  for (int t = 0; t < 4; ++t) { loadT(t0 + t, BA, eA); compute(BA, eA, t0 + t, false); }
  publish();
  __syncthreads();
  refreshThr();

  // main scan: reg double-buffered, no barriers
  loadT(t0, BA, eA);
  for (int i = 0; i < TPW; i += 2) {
    loadT(t0 + i + 1, BB, eB);
    compute(BA, eA, t0 + i, true);
    if (i + 2 < TPW) loadT(t0 + i + 2, BA, eA);
    compute(BB, eB, t0 + i + 1, true);
    if (i & 2) { publish(); refreshThr(); }   // every 4 tiles
  }
  __syncthreads();

  // ---- exact rescore (bit-identical round-0 scoring), output, loss ----
  double s1 = 0.0, s2 = 0.0;
  if (tid < BM) {
    const int grow = rowbase + tid;
    const int cnt = s_cnt[tid];
    if (cnt > CAP) {
      const int gi = atomicAdd(ovfc, 1);
      ovfr[gi] = grow;
    } else {
      float f[DIM];
      #pragma unroll
      for (int j = 0; j < 16; ++j) {
        const float4 v = ldg4(x + (size_t)grow * DIM + 4 * j);
        f[4 * j] = v.x; f[4 * j + 1] = v.y; f[4 * j + 2] = v.z; f[4 * j + 3] = v.w;
      }
      float r8[8];
      #pragma unroll
      for (int j = 0; j < 8; ++j) r8[j] = __fmul_rn(f[j], f[j]);
      #pragma unroll
      for (int i = 1; i < 8; ++i)
        #pragma unroll
        for (int j = 0; j < 8; ++j)
          r8[j] = __fadd_rn(r8[j], __fmul_rn(f[8 * i + j], f[8 * i + j]));
      const float fn = __fadd_rn(
          __fadd_rn(__fadd_rn(r8[0], r8[1]), __fadd_rn(r8[2], r8[3])),
          __fadd_rn(__fadd_rn(r8[4], r8[5]), __fadd_rn(r8[6], r8[7])));
      float dbest = 3.4e38f; int kbest = 0x7FFFFFFF;
      for (int i = 0; i < cnt; ++i) {
        const int k = s_list[tid][i];
        const float* ep = embt + (size_t)k * DIM;
        float dot = 0.f;
        #pragma unroll
        for (int j = 0; j < DIM / 4; ++j) {
          const float4 e4 = ldg4(ep + 4 * j);
          dot = fmaf(f[4 * j + 0], e4.x, dot);
          dot = fmaf(f[4 * j + 1], e4.y, dot);
          dot = fmaf(f[4 * j + 2], e4.z, dot);
          dot = fmaf(f[4 * j + 3], e4.w, dot);
        }
        const float d = __fsub_rn(__fadd_rn(fn, en[k]), __fmul_rn(2.0f, dot));
        if (d < dbest || (d == dbest && k < kbest)) { dbest = d; kbest = k; }
      }
      const float* qp = embt + (size_t)kbest * DIM;
      #pragma unroll
      for (int j = 0; j < 16; ++j) {
        const float4 q = ldg4(qp + 4 * j);
        *reinterpret_cast<float4*>(&out[(size_t)grow * DIM + 4 * j]) = q;
        const float d0 = __fsub_rn(q.x, f[4 * j + 0]);
        const float d1 = __fsub_rn(q.y, f[4 * j + 1]);
        const float d2 = __fsub_rn(q.z, f[4 * j + 2]);
        const float d3 = __fsub_rn(q.w, f[4 * j + 3]);
        s1 += ((double)d0 + (double)d1) + ((double)d2 + (double)d3);
        s2 += ((double)d0 * d0 + (double)d1 * d1) + ((double)d2 * d2 + (double)d3 * d3);
      }
    }
    // wave-0 reduction (tid<64 == wave 0)
    #pragma unroll
    for (int off = 32; off > 0; off >>= 1) {
      s1 += __shfl_down(s1, off, 64);
      s2 += __shfl_down(s2, off, 64);
    }
    if (tid == 0) { atomicAdd(&red[0], s1); atomicAdd(&red[1], s2); }
  }
}

// ---- fallback: full exact scan for overflow rows (expected ~0) ----
__global__ __launch_bounds__(256) void vq_fallback(
    const float* __restrict__ x, const float* __restrict__ embt,
    const float* __restrict__ en, float* __restrict__ out,
    double* __restrict__ red, const int* __restrict__ ovfc,
    const int* __restrict__ ovfr) {
  const int n = *ovfc;
  const int gw = (blockIdx.x * 256 + threadIdx.x) >> 6;
  const int lane = threadIdx.x & 63;
  const int nw = gridDim.x * 4;
  for (int i = gw; i < n; i += nw) {
    const int row = ovfr[i];
    float f[DIM];
    #pragma unroll
    for (int j = 0; j < 16; ++j) {
      const float4 v = ldg4(x + (size_t)row * DIM + 4 * j);
      f[4 * j] = v.x; f[4 * j + 1] = v.y; f[4 * j + 2] = v.z; f[4 * j + 3] = v.w;
    }
    float r8[8];
    #pragma unroll
    for (int j = 0; j < 8; ++j) r8[j] = __fmul_rn(f[j], f[j]);
    #pragma unroll
    for (int ii = 1; ii < 8; ++ii)
      #pragma unroll
      for (int j = 0; j < 8; ++j)
        r8[j] = __fadd_rn(r8[j], __fmul_rn(f[8 * ii + j], f[8 * ii + j]));
    const float fn = __fadd_rn(
        __fadd_rn(__fadd_rn(r8[0], r8[1]), __fadd_rn(r8[2], r8[3])),
        __fadd_rn(__fadd_rn(r8[4], r8[5]), __fadd_rn(r8[6], r8[7])));
    float dbest = 3.4e38f; int kbest = 0x7FFFFFFF;
    for (int j = 0; j < KCODES / 64; ++j) {
      const int k = j * 64 + lane;
      const float* ep = embt + (size_t)k * DIM;
      float dot = 0.f;
      #pragma unroll
      for (int jj = 0; jj < 16; ++jj) {
        const float4 e4 = ldg4(ep + 4 * jj);
        dot = fmaf(f[4 * jj + 0], e4.x, dot);
        dot = fmaf(f[4 * jj + 1], e4.y, dot);
        dot = fmaf(f[4 * jj + 2], e4.z, dot);
        dot = fmaf(f[4 * jj + 3], e4.w, dot);
      }
      const float d = __fsub_rn(__fadd_rn(fn, en[k]), __fmul_rn(2.0f, dot));
      if (d < dbest) { dbest = d; kbest = k; }
    }
    #pragma unroll
    for (int off = 32; off > 0; off >>= 1) {
      const float d2 = __shfl_xor(dbest, off, 64);
      const int k2 = __shfl_xor(kbest, off, 64);
      if (d2 < dbest || (d2 == dbest && k2 < kbest)) { dbest = d2; kbest = k2; }
    }
    double s1 = 0.0, s2 = 0.0;
    if (lane < 16) {
      const float4 q = ldg4(embt + (size_t)kbest * DIM + lane * 4);
      *reinterpret_cast<float4*>(&out[(size_t)row * DIM + lane * 4]) = q;
      const float d0 = __fsub_rn(q.x, f[lane * 4 + 0]);
      const float d1 = __fsub_rn(q.y, f[lane * 4 + 1]);
      const float d2 = __fsub_rn(q.z, f[lane * 4 + 2]);
      const float d3 = __fsub_rn(q.w, f[lane * 4 + 3]);
      s1 = ((double)d0 + (double)d1) + ((double)d2 + (double)d3);
      s2 = ((double)d0 * d0 + (double)d1 * d1) + ((double)d2 * d2 + (double)d3 * d3);
    }
    #pragma unroll
    for (int off = 32; off > 0; off >>= 1) {
      s1 += __shfl_down(s1, off, 64);
      s2 += __shfl_down(s2, off, 64);
    }
    if (lane == 0) { atomicAdd(&red[0], s1); atomicAdd(&red[1], s2); }
  }
}

__global__ void vq_loss(const double* __restrict__ red, float* __restrict__ out) {
  const double inv = 1.0 / (double)((long long)NROWS * DIM);
  const double m1 = red[0] * inv;
  const double m2 = red[1] * inv;
  out[(long long)NROWS * DIM] = (float)(0.25 * m1 * m1 + m2);
}

extern "C" void kernel_launch(void* const* d_in, const int* in_sizes, int n_in,
                              void* d_out, int out_size, void* d_ws, size_t ws_size,
                              hipStream_t stream) {
  const float* x   = (const float*)d_in[0];
  const float* emb = (const float*)d_in[1];
  float* out = (float*)d_out;
  char* ws = (char*)d_ws;
  double*    red  = (double*)ws;
  int*       ovfc = (int*)(ws + WS_OVFC);
  int*       ovfr = (int*)(ws + WS_OVFR);
  float*     en   = (float*)(ws + WS_EN);
  float*     en2  = (float*)(ws + WS_EN2);
  float*     embt = (float*)(ws + WS_EMBT);
  _Float16*  frag = (_Float16*)(ws + WS_FRAG);
  hipMemsetAsync(d_ws, 0, 128, stream);
  vq_enorm<<<4, 256, 0, stream>>>(emb, en, en2);
  prep_t<<<16, 256, 0, stream>>>(emb, embt, frag);
  vq_scan<<<NBLK, 256, 0, stream>>>(x, frag, en2, embt, en, out, red, ovfc, ovfr);
  vq_fallback<<<16, 256, 0, stream>>>(x, embt, en, out, red, ovfc, ovfr);
  vq_loss<<<1, 1, 0, stream>>>(red, out);
}